// Round 13
// baseline (166.877 us; speedup 1.0000x reference)
//
#include <hip/hip_runtime.h>
#include <hip/hip_fp16.h>
#include <math.h>

#define Bv   16
#define Nv   256
#define Dv   512
#define Hv   8
#define MNv  4096          // B*N tokens

typedef __attribute__((ext_vector_type(4))) float f32x4;
typedef __fp16 fp16x8 __attribute__((ext_vector_type(8)));
typedef __fp16 fp16x2 __attribute__((ext_vector_type(2)));

__device__ __forceinline__ void gload_lds16(const void* g, void* l) {
    __builtin_amdgcn_global_load_lds(
        (const __attribute__((address_space(1))) unsigned int*)g,
        (__attribute__((address_space(3))) unsigned int*)l, 16, 0, 0);
}

// Raw HW transcendentals.
__device__ __forceinline__ void fast_sincos(float x, float* s, float* c) {
    const float rev = x * 0.15915494309189535f;   // v_sin takes revolutions
    const float fr  = rev - floorf(rev);
    *s = __builtin_amdgcn_sinf(fr);
    *c = __builtin_amdgcn_cosf(fr);
}
__device__ __forceinline__ float fast_log(float x) {
    return __builtin_amdgcn_logf(x) * 0.6931471805599453f;
}
__device__ __forceinline__ float fast_exp(float x) {
    return __builtin_amdgcn_exp2f(x * 1.4426950408889634f);
}
__device__ __forceinline__ unsigned short f2h(float x) {    // 1 instr v_cvt_f16_f32
    return __half_as_ushort(__float2half(x));
}

// ---------------------------------------------------------------------------
// MEGA-1: geo-bias (blocks 0..4095) + weight transpose fp32->f16 (4096..4351).
// ---------------------------------------------------------------------------
__global__ __launch_bounds__(256) void mega1_kernel(
    const float* __restrict__ box, const int* __restrict__ mask,
    const float* __restrict__ WGw, const float* __restrict__ WGb,
    __half* __restrict__ LB,
    const float* __restrict__ Wq, const float* __restrict__ Wk,
    const float* __restrict__ Wv, const float* __restrict__ Wo,
    const float* __restrict__ bq, const float* __restrict__ bk,
    const float* __restrict__ bv, const float* __restrict__ bo,
    unsigned short* __restrict__ Wt, float* __restrict__ biasStack)
{
    __shared__ __align__(16) char smraw[64 * 65 * 4];   // union: geo Lst / conv_w T
    const int bid = blockIdx.x;
    const int t = threadIdx.x;

    if (bid < 4096) {
        // ================= geo-bias =================
        unsigned short (*Lst)[264] = (unsigned short (*)[264])smraw;
        const int q = bid & 255;
        const int b = bid >> 8;
        const int w = t >> 6, lane = t & 63;
        const int n = lane & 15;
        const int quad = lane >> 4;

        const float4 bq_ = *(const float4*)(box + (b * Nv + q) * 4);
        const float cxq = (bq_.x + bq_.z) * 0.5f;
        const float cyq = (bq_.y + bq_.w) * 0.5f;
        const float wq  = bq_.z - bq_.x + 1.0f;
        const float hq  = bq_.w - bq_.y + 1.0f;

        union F16x8 { fp16x8 v; fp16x2 p[4]; };
        F16x8 Bs_, Bc_;
        Bs_.v = (fp16x8){}; Bc_.v = (fp16x8){};
        float bias_n = 0.0f;
        if (n < Hv) {
            bias_n = WGb[n];
#pragma unroll
            for (int jj = 0; jj < 4; ++jj) {
                Bs_.p[jj] = __builtin_amdgcn_cvt_pkrtz(WGw[n * 64 + quad * 8 + 2 * jj],
                                                       WGw[n * 64 + quad * 8 + 2 * jj + 1]);
                Bc_.p[jj] = __builtin_amdgcn_cvt_pkrtz(WGw[n * 64 + 32 + quad * 8 + 2 * jj],
                                                       WGw[n * 64 + 32 + quad * 8 + 2 * jj + 1]);
            }
        }

        const float dimm[8] = {1.0f, 0.42169650342f, 0.17782794100f, 0.07498942093f,
                               0.03162277660f, 0.01333521432f, 0.00562341325f, 0.00237137371f};
        const bool isCtr = (quad < 2);
        const bool isY   = (quad & 1);
        const float cq  = isY ? cyq : cxq;
        const float sq_ = isY ? hq : wq;

#pragma unroll
        for (int i = 0; i < 4; ++i) {
            const int m0 = (w * 4 + i) * 16;
            const float4 bm = *(const float4*)(box + (b * Nv + m0 + n) * 4);
            const float cxm = (bm.x + bm.z) * 0.5f;
            const float cym = (bm.y + bm.w) * 0.5f;
            const float wm  = bm.z - bm.x + 1.0f;
            const float hm  = bm.w - bm.y + 1.0f;
            const float cm_ = isY ? cym : cxm;
            const float sm_ = isY ? hm : wm;
            const float top = isCtr ? fabsf(cq - cm_) : sq_;
            const float bot = isCtr ? sq_ : sm_;
            float r = top * __builtin_amdgcn_rcpf(bot);
            if (isCtr) r = fmaxf(r, 1e-3f);
            const float base = 69.31471805599453f * __builtin_amdgcn_logf(r);

            float sv[8], cv[8];
#pragma unroll
            for (int j = 0; j < 8; ++j)
                fast_sincos(base * dimm[j], &sv[j], &cv[j]);

            F16x8 As_, Ac_;
#pragma unroll
            for (int jj = 0; jj < 4; ++jj) {
                As_.p[jj] = __builtin_amdgcn_cvt_pkrtz(sv[2 * jj], sv[2 * jj + 1]);
                Ac_.p[jj] = __builtin_amdgcn_cvt_pkrtz(cv[2 * jj], cv[2 * jj + 1]);
            }

            f32x4 acc = {};
            acc = __builtin_amdgcn_mfma_f32_16x16x32_f16(As_.v, Bs_.v, acc, 0, 0, 0);
            acc = __builtin_amdgcn_mfma_f32_16x16x32_f16(Ac_.v, Bc_.v, acc, 0, 0, 0);

            const int mrow = m0 + quad * 4;
            const int4 mk = *(const int4*)(mask + b * Nv + mrow);
            if (n < Hv) {
                const int* mkp = (const int*)&mk;
                const int pos0 = quad * 64 + (w * 4 + i);
#pragma unroll
                for (int rr = 0; rr < 4; ++rr) {
                    const float val = fmaxf(acc[rr] + bias_n, 1e-6f);
                    const float lb = fast_log(val) + (mkp[rr] ? 0.0f : -30000.0f);
                    Lst[n][pos0 + rr * 16] = f2h(lb);
                }
            }
        }

        __syncthreads();
        const int h = t >> 5, c = t & 31;
        unsigned short* dst = (unsigned short*)LB +
                              ((size_t)(b * Hv + h) * Nv + q) * Nv + c * 8;
        *(int4*)dst = *(const int4*)&Lst[h][c * 8];

    } else {
        // ================= weight transpose fp32 W[k][n] -> f16 Wt[n][k] =====
        float (*T)[65] = (float (*)[65])smraw;
        const int i = bid - 4096;          // 0..255
        const int z = i >> 6;
        const int rem = i & 63;
        const int n0 = (rem & 7) * 64, k0 = (rem >> 3) * 64;
        const float* W = (z == 0) ? Wq : (z == 1) ? Wk : (z == 2) ? Wv : Wo;
        const float* b = (z == 0) ? bq : (z == 1) ? bk : (z == 2) ? bv : bo;
        const int col = t & 63, rb = t >> 6;
#pragma unroll
        for (int j = 0; j < 16; ++j) {
            const int row = j * 4 + rb;
            T[row][col] = W[(k0 + row) * Dv + n0 + col];
        }
        __syncthreads();
#pragma unroll
        for (int j = 0; j < 16; ++j) {
            const int row = j * 4 + rb;
            Wt[z * (Dv * Dv) + (n0 + row) * Dv + k0 + col] = f2h(T[col][row]);
        }
        if (rem == 0) {
            biasStack[z * Dv + t]       = b[t];
            biasStack[z * Dv + t + 256] = b[t + 256];
        }
    }
}

// ---------------------------------------------------------------------------
// Fused Q/K/V projection GEMM, fp32-A-direct: stages the ORIGINAL fp32 inputs
// with v_cvt_pkrtz -> f16 LDS (no bf16 conversion pre-pass kernel).
// 128x64 tile, grid (8,32,3) = 768 blocks.  z=0: Q f16 scaled 1/8; z=1: K f16;
// z=2: V f16 transposed per-batch [b][d][m].
// ---------------------------------------------------------------------------
__global__ __launch_bounds__(256) void qkv_gemm_kernel(
    const float* __restrict__ xq, const float* __restrict__ xk,
    const float* __restrict__ xv, const unsigned short* __restrict__ Wt,
    const float* __restrict__ bst, unsigned short* __restrict__ Qb2,
    unsigned short* __restrict__ Kb2, unsigned short* __restrict__ Vt2)
{
    const int z = blockIdx.z;
    const float* A = (z == 0) ? xq : (z == 1) ? xk : xv;
    const unsigned short* Wz = Wt + (size_t)z * (Dv * Dv);
    const float* bias = bst + z * Dv;

    const int n0 = blockIdx.x * 64;
    const int m0 = blockIdx.y * 128;
    const int t = threadIdx.x;
    const int w = t >> 6, lane = t & 63;
    const int wm = w & 1, wn = w >> 1;

    __shared__ unsigned short As[128][32];   // f16
    __shared__ unsigned short Bs[64][32];    // f16

    f32x4 acc[4][2] = {};

    const int arow = t >> 1;                 // A staging: 2 threads per row
    const int ahalf = (t & 1) * 16;          // 16 floats each
    const int sr = lane >> 2;                // B staging (global_load_lds)
    const int sk = (lane & 3) * 8;
    const int fr = lane & 15;
    const int fk = (lane >> 4) * 8;

    union V16 { fp16x2 p[4]; int4 v; };

    for (int k0 = 0; k0 < Dv; k0 += 32) {
        // issue fp32 A loads before the barrier (latency overlap)
        const float* ap = A + (size_t)(m0 + arow) * Dv + k0 + ahalf;
        const float4 a0 = *(const float4*)(ap);
        const float4 a1 = *(const float4*)(ap + 4);
        const float4 a2 = *(const float4*)(ap + 8);
        const float4 a3 = *(const float4*)(ap + 12);
        __syncthreads();
        gload_lds16(Wz + (size_t)(n0 + w * 16 + sr) * Dv + k0 + sk, &Bs[w * 16][0]);
        V16 u0, u1;
        u0.p[0] = __builtin_amdgcn_cvt_pkrtz(a0.x, a0.y);
        u0.p[1] = __builtin_amdgcn_cvt_pkrtz(a0.z, a0.w);
        u0.p[2] = __builtin_amdgcn_cvt_pkrtz(a1.x, a1.y);
        u0.p[3] = __builtin_amdgcn_cvt_pkrtz(a1.z, a1.w);
        u1.p[0] = __builtin_amdgcn_cvt_pkrtz(a2.x, a2.y);
        u1.p[1] = __builtin_amdgcn_cvt_pkrtz(a2.z, a2.w);
        u1.p[2] = __builtin_amdgcn_cvt_pkrtz(a3.x, a3.y);
        u1.p[3] = __builtin_amdgcn_cvt_pkrtz(a3.z, a3.w);
        *(int4*)&As[arow][ahalf]     = u0.v;
        *(int4*)&As[arow][ahalf + 8] = u1.v;
        __syncthreads();

        fp16x8 af[4], bfr[2];
#pragma unroll
        for (int mt = 0; mt < 4; ++mt)
            af[mt] = *(const fp16x8*)&As[wm * 64 + mt * 16 + fr][fk];
#pragma unroll
        for (int nt = 0; nt < 2; ++nt)
            bfr[nt] = *(const fp16x8*)&Bs[wn * 32 + nt * 16 + fr][fk];
#pragma unroll
        for (int mt = 0; mt < 4; ++mt)
#pragma unroll
            for (int nt = 0; nt < 2; ++nt)
                acc[mt][nt] = __builtin_amdgcn_mfma_f32_16x16x32_f16(
                    af[mt], bfr[nt], acc[mt][nt], 0, 0, 0);
    }

    const int er = (lane >> 4) * 4;
    const int ec = lane & 15;
    const float scale = (z == 0) ? 0.125f : 1.0f;
#pragma unroll
    for (int nt = 0; nt < 2; ++nt) {
        const int gn = n0 + wn * 32 + nt * 16 + ec;
        const float bv_ = bias[gn];
#pragma unroll
        for (int mt = 0; mt < 4; ++mt) {
            const int gm = m0 + wm * 64 + mt * 16 + er;
            if (z == 2) {
                union { fp16x2 p[2]; ushort4 u; } o;
                o.p[0] = __builtin_amdgcn_cvt_pkrtz(acc[mt][nt][0] + bv_,
                                                    acc[mt][nt][1] + bv_);
                o.p[1] = __builtin_amdgcn_cvt_pkrtz(acc[mt][nt][2] + bv_,
                                                    acc[mt][nt][3] + bv_);
                *(ushort4*)(Vt2 + ((size_t)(gm >> 8) * Dv + gn) * Nv + (gm & 255)) = o.u;
            } else {
                unsigned short* cp = ((z == 0) ? Qb2 : Kb2) + (size_t)gm * Dv + gn;
#pragma unroll
                for (int r = 0; r < 4; ++r)
                    cp[(size_t)r * Dv] = f2h((acc[mt][nt][r] + bv_) * scale);
            }
        }
    }
}

// ---------------------------------------------------------------------------
// Output GEMM: out[4096][512] = CTXh(f16) @ Wo^T + bias, fp32.  128x64 tile,
// grid (8,32) = 256 blocks.
// ---------------------------------------------------------------------------
__global__ __launch_bounds__(256) void out_gemm_kernel(
    const unsigned short* __restrict__ A, const unsigned short* __restrict__ Wz,
    const float* __restrict__ bias, float* __restrict__ C)
{
    const int n0 = blockIdx.x * 64;
    const int m0 = blockIdx.y * 128;
    const int t = threadIdx.x;
    const int w = t >> 6, lane = t & 63;
    const int wm = w & 1, wn = w >> 1;

    __shared__ unsigned short As[128][32];
    __shared__ unsigned short Bs[64][32];

    f32x4 acc[4][2] = {};

    const int sr = lane >> 2;
    const int sk = (lane & 3) * 8;
    const int fr = lane & 15;
    const int fk = (lane >> 4) * 8;

    for (int k0 = 0; k0 < Dv; k0 += 32) {
        __syncthreads();
#pragma unroll
        for (int j = 0; j < 2; ++j) {
            const int row = w * 32 + j * 16 + sr;
            gload_lds16(A + (size_t)(m0 + row) * Dv + k0 + sk, &As[w * 32 + j * 16][0]);
        }
        gload_lds16(Wz + (size_t)(n0 + w * 16 + sr) * Dv + k0 + sk, &Bs[w * 16][0]);
        __syncthreads();

        fp16x8 af[4], bfr[2];
#pragma unroll
        for (int mt = 0; mt < 4; ++mt)
            af[mt] = *(const fp16x8*)&As[wm * 64 + mt * 16 + fr][fk];
#pragma unroll
        for (int nt = 0; nt < 2; ++nt)
            bfr[nt] = *(const fp16x8*)&Bs[wn * 32 + nt * 16 + fr][fk];
#pragma unroll
        for (int mt = 0; mt < 4; ++mt)
#pragma unroll
            for (int nt = 0; nt < 2; ++nt)
                acc[mt][nt] = __builtin_amdgcn_mfma_f32_16x16x32_f16(
                    af[mt], bfr[nt], acc[mt][nt], 0, 0, 0);
    }

    const int er = (lane >> 4) * 4;
    const int ec = lane & 15;
#pragma unroll
    for (int nt = 0; nt < 2; ++nt) {
        const int gn = n0 + wn * 32 + nt * 16 + ec;
        const float bv_ = bias[gn];
#pragma unroll
        for (int mt = 0; mt < 4; ++mt) {
            const int gm = m0 + wm * 64 + mt * 16 + er;
            float* cp = C + (size_t)gm * Dv + gn;
#pragma unroll
            for (int r = 0; r < 4; ++r)
                cp[(size_t)r * Dv] = acc[mt][nt][r] + bv_;
        }
    }
}

// ---------------------------------------------------------------------------
// attn3 (MFMA, f16): block=(64q, h, b), 4 waves; wave owns 16 q rows.
// LB (permuted) preloaded as MFMA C accumulator; Q pre-scaled 1/8.
// Softmax in registers (HW v_exp/v_rcp); P -> LDS (aliasing dead K); PV vs V^T.
// ---------------------------------------------------------------------------
__global__ __launch_bounds__(256) void attn3_kernel(
    const unsigned short* __restrict__ Qb2, const unsigned short* __restrict__ Kb2,
    const unsigned short* __restrict__ Vt2, const __half* __restrict__ LB,
    unsigned short* __restrict__ CTXh)
{
    const int qt = blockIdx.x, h = blockIdx.y, b = blockIdx.z;
    const int q0 = qt * 64;
    const int t = threadIdx.x, w = t >> 6, lane = t & 63;
    const int fr = lane & 15, fq = lane >> 4;

    __shared__ unsigned short Qs[64][72];
    __shared__ unsigned short Ks[256][72];
    __shared__ unsigned short Vt[64][264];
    unsigned short (*Pb)[264] = (unsigned short (*)[264])&Ks[0][0];

#pragma unroll
    for (int i = 0; i < 2; ++i) {          // Q
        const int idx = t + i * 256;
        const int row = idx >> 3, cu = idx & 7;
        *(int4*)&Qs[row][cu * 8] =
            *(const int4*)(Qb2 + (size_t)(b * Nv + q0 + row) * Dv + h * 64 + cu * 8);
    }
#pragma unroll
    for (int i = 0; i < 8; ++i) {          // K
        const int idx = t + i * 256;
        const int row = idx >> 3, cu = idx & 7;
        *(int4*)&Ks[row][cu * 8] =
            *(const int4*)(Kb2 + (size_t)(b * Nv + row) * Dv + h * 64 + cu * 8);
    }
#pragma unroll
    for (int i = 0; i < 8; ++i) {          // V^T
        const int idx = t + i * 256;
        const int row = idx >> 5, cu = idx & 31;
        *(int4*)&Vt[row][cu * 8] =
            *(const int4*)(Vt2 + (size_t)b * (Dv * Nv) + (h * 64 + row) * Nv + cu * 8);
    }

    // ---- acc init from permuted LB: row q=qb+r, 16 contiguous halfs @ fr*16
    f32x4 acc[16];
    const int qb = q0 + w * 16 + fq * 4;
    const __half* lbp = LB + ((size_t)(b * Hv + h) * Nv + qb) * Nv + fr * 16;
#pragma unroll
    for (int r = 0; r < 4; ++r) {
        union { int4 v; __half hs[8]; } u0, u1;
        const int4* p = (const int4*)(lbp + (size_t)r * Nv);
        u0.v = p[0]; u1.v = p[1];
#pragma unroll
        for (int nt = 0; nt < 8; ++nt) acc[nt][r]     = __half2float(u0.hs[nt]);
#pragma unroll
        for (int nt = 0; nt < 8; ++nt) acc[nt + 8][r] = __half2float(u1.hs[nt]);
    }

    __syncthreads();

    // ---- QK^T ----
    const fp16x8 aq0 = *(const fp16x8*)&Qs[w * 16 + fr][fq * 8];
    const fp16x8 aq1 = *(const fp16x8*)&Qs[w * 16 + fr][32 + fq * 8];
#pragma unroll
    for (int nt = 0; nt < 16; ++nt) {
        const fp16x8 bk0 = *(const fp16x8*)&Ks[nt * 16 + fr][fq * 8];
        const fp16x8 bk1 = *(const fp16x8*)&Ks[nt * 16 + fr][32 + fq * 8];
        acc[nt] = __builtin_amdgcn_mfma_f32_16x16x32_f16(aq0, bk0, acc[nt], 0, 0, 0);
        acc[nt] = __builtin_amdgcn_mfma_f32_16x16x32_f16(aq1, bk1, acc[nt], 0, 0, 0);
    }

    // ---- softmax in registers (HW exp2/rcp) ----
    float ri[4];
#pragma unroll
    for (int r = 0; r < 4; ++r) {
        float mx = acc[0][r];
#pragma unroll
        for (int nt = 1; nt < 16; ++nt) mx = fmaxf(mx, acc[nt][r]);
        mx = fmaxf(mx, __shfl_xor(mx, 1));
        mx = fmaxf(mx, __shfl_xor(mx, 2));
        mx = fmaxf(mx, __shfl_xor(mx, 4));
        mx = fmaxf(mx, __shfl_xor(mx, 8));
        float s = 0.0f;
#pragma unroll
        for (int nt = 0; nt < 16; ++nt) {
            const float e = fast_exp(acc[nt][r] - mx);
            acc[nt][r] = e;
            s += e;
        }
        s += __shfl_xor(s, 1);
        s += __shfl_xor(s, 2);
        s += __shfl_xor(s, 4);
        s += __shfl_xor(s, 8);
        ri[r] = __builtin_amdgcn_rcpf(s);
    }

    __syncthreads();   // all Ks reads complete before P overwrites the buffer

#pragma unroll
    for (int nt = 0; nt < 16; ++nt)
#pragma unroll
        for (int r = 0; r < 4; ++r)
            Pb[w * 16 + fq * 4 + r][nt * 16 + fr] = f2h(acc[nt][r] * ri[r]);

    // ---- PV ----
    f32x4 o[4] = {};
#pragma unroll
    for (int kt = 0; kt < 8; ++kt) {
        const fp16x8 ap = *(const fp16x8*)&Pb[w * 16 + fr][kt * 32 + fq * 8];
#pragma unroll
        for (int nt2 = 0; nt2 < 4; ++nt2) {
            const fp16x8 bv_ = *(const fp16x8*)&Vt[nt2 * 16 + fr][kt * 32 + fq * 8];
            o[nt2] = __builtin_amdgcn_mfma_f32_16x16x32_f16(ap, bv_, o[nt2], 0, 0, 0);
        }
    }

#pragma unroll
    for (int nt2 = 0; nt2 < 4; ++nt2)
#pragma unroll
        for (int r = 0; r < 4; ++r)
            CTXh[(size_t)(b * Nv + qb + r) * Dv + h * 64 + nt2 * 16 + fr] =
                f2h(o[nt2][r]);
}

// ---------------------------------------------------------------------------
extern "C" void kernel_launch(void* const* d_in, const int* in_sizes, int n_in,
                              void* d_out, int out_size, void* d_ws, size_t ws_size,
                              hipStream_t stream) {
    (void)in_sizes; (void)n_in; (void)out_size; (void)ws_size;

    const float* inq  = (const float*)d_in[0];
    const float* ink  = (const float*)d_in[1];
    const float* inv  = (const float*)d_in[2];
    const float* box  = (const float*)d_in[3];
    const int*   mask = (const int*)d_in[4];
    const float* Wq   = (const float*)d_in[5];
    const float* bq   = (const float*)d_in[6];
    const float* Wk   = (const float*)d_in[7];
    const float* bk   = (const float*)d_in[8];
    const float* Wv   = (const float*)d_in[9];
    const float* bv   = (const float*)d_in[10];
    const float* Wo   = (const float*)d_in[11];
    const float* bo   = (const float*)d_in[12];
    const float* WGw  = (const float*)d_in[13];
    const float* WGb  = (const float*)d_in[14];

    char* W = (char*)d_ws;
    const size_t MB = 1048576;
    unsigned short* Qb2  = (unsigned short*)(W + 0);        // 4 MB f16, pre-scaled 1/8
    unsigned short* Kb2  = (unsigned short*)(W + 4 * MB);   // 4 MB f16
    unsigned short* Vt2  = (unsigned short*)(W + 8 * MB);   // 4 MB f16 [b][d][m]
    unsigned short* Wt   = (unsigned short*)(W + 12 * MB);  // 2 MB (4 transposed f16 weights)
    float*          bst  = (float*)(W + 14 * MB);           // 8 KB
    unsigned short* CTXh = (unsigned short*)(W + 15 * MB);  // 4 MB f16
    __half*         LB   = (__half*)(W + 20 * MB);          // 16.8 MB

    float* out = (float*)d_out;

    mega1_kernel<<<4352, 256, 0, stream>>>(
        box, mask, WGw, WGb, LB,
        Wq, Wk, Wv, Wo, bq, bk, bv, bo, Wt, bst);

    qkv_gemm_kernel<<<dim3(8, 32, 3), 256, 0, stream>>>(
        inq, ink, inv, Wt, bst, Qb2, Kb2, Vt2);

    attn3_kernel<<<dim3(4, 8, 16), 256, 0, stream>>>(Qb2, Kb2, Vt2, LB, CTXh);

    out_gemm_kernel<<<dim3(8, 32), 256, 0, stream>>>(CTXh, Wt + 3 * (Dv * Dv), bst + 3 * Dv, out);
}

// Round 14
// 166.822 us; speedup vs baseline: 1.0003x; 1.0003x over previous
//
#include <hip/hip_runtime.h>
#include <hip/hip_fp16.h>
#include <math.h>

#define Bv   16
#define Nv   256
#define Dv   512
#define Hv   8
#define MNv  4096          // B*N tokens

typedef __attribute__((ext_vector_type(4))) float f32x4;
typedef __fp16 fp16x8 __attribute__((ext_vector_type(8)));
typedef __fp16 fp16x2 __attribute__((ext_vector_type(2)));

__device__ __forceinline__ void gload_lds16(const void* g, void* l) {
    __builtin_amdgcn_global_load_lds(
        (const __attribute__((address_space(1))) unsigned int*)g,
        (__attribute__((address_space(3))) unsigned int*)l, 16, 0, 0);
}

// Raw HW transcendentals.
__device__ __forceinline__ void fast_sincos(float x, float* s, float* c) {
    const float rev = x * 0.15915494309189535f;   // v_sin takes revolutions
    const float fr  = rev - floorf(rev);
    *s = __builtin_amdgcn_sinf(fr);
    *c = __builtin_amdgcn_cosf(fr);
}
__device__ __forceinline__ float fast_log(float x) {
    return __builtin_amdgcn_logf(x) * 0.6931471805599453f;
}
__device__ __forceinline__ float fast_exp(float x) {
    return __builtin_amdgcn_exp2f(x * 1.4426950408889634f);
}
__device__ __forceinline__ unsigned short f2h(float x) {
    return __half_as_ushort(__float2half(x));
}

// ---------------------------------------------------------------------------
// MEGA-1: geo-bias (blocks 0..4095) + weight transpose fp32->f16 (4096..4351).
// ---------------------------------------------------------------------------
__global__ __launch_bounds__(256) void mega1_kernel(
    const float* __restrict__ box, const int* __restrict__ mask,
    const float* __restrict__ WGw, const float* __restrict__ WGb,
    __half* __restrict__ LB,
    const float* __restrict__ Wq, const float* __restrict__ Wk,
    const float* __restrict__ Wv, const float* __restrict__ Wo,
    const float* __restrict__ bq, const float* __restrict__ bk,
    const float* __restrict__ bv, const float* __restrict__ bo,
    unsigned short* __restrict__ Wt, float* __restrict__ biasStack)
{
    __shared__ __align__(16) char smraw[64 * 65 * 4];   // union: geo Lst / conv_w T
    const int bid = blockIdx.x;
    const int t = threadIdx.x;

    if (bid < 4096) {
        // ================= geo-bias =================
        unsigned short (*Lst)[264] = (unsigned short (*)[264])smraw;
        const int q = bid & 255;
        const int b = bid >> 8;
        const int w = t >> 6, lane = t & 63;
        const int n = lane & 15;
        const int quad = lane >> 4;

        const float4 bq_ = *(const float4*)(box + (b * Nv + q) * 4);
        const float cxq = (bq_.x + bq_.z) * 0.5f;
        const float cyq = (bq_.y + bq_.w) * 0.5f;
        const float wq  = bq_.z - bq_.x + 1.0f;
        const float hq  = bq_.w - bq_.y + 1.0f;

        union F16x8 { fp16x8 v; fp16x2 p[4]; };
        F16x8 Bs_, Bc_;
        Bs_.v = (fp16x8){}; Bc_.v = (fp16x8){};
        float bias_n = 0.0f;
        if (n < Hv) {
            bias_n = WGb[n];
#pragma unroll
            for (int jj = 0; jj < 4; ++jj) {
                Bs_.p[jj] = __builtin_amdgcn_cvt_pkrtz(WGw[n * 64 + quad * 8 + 2 * jj],
                                                       WGw[n * 64 + quad * 8 + 2 * jj + 1]);
                Bc_.p[jj] = __builtin_amdgcn_cvt_pkrtz(WGw[n * 64 + 32 + quad * 8 + 2 * jj],
                                                       WGw[n * 64 + 32 + quad * 8 + 2 * jj + 1]);
            }
        }

        const float dimm[8] = {1.0f, 0.42169650342f, 0.17782794100f, 0.07498942093f,
                               0.03162277660f, 0.01333521432f, 0.00562341325f, 0.00237137371f};
        const bool isCtr = (quad < 2);
        const bool isY   = (quad & 1);
        const float cq  = isY ? cyq : cxq;
        const float sq_ = isY ? hq : wq;

#pragma unroll
        for (int i = 0; i < 4; ++i) {
            const int m0 = (w * 4 + i) * 16;
            const float4 bm = *(const float4*)(box + (b * Nv + m0 + n) * 4);
            const float cxm = (bm.x + bm.z) * 0.5f;
            const float cym = (bm.y + bm.w) * 0.5f;
            const float wm  = bm.z - bm.x + 1.0f;
            const float hm  = bm.w - bm.y + 1.0f;
            const float cm_ = isY ? cym : cxm;
            const float sm_ = isY ? hm : wm;
            const float top = isCtr ? fabsf(cq - cm_) : sq_;
            const float bot = isCtr ? sq_ : sm_;
            float r = top * __builtin_amdgcn_rcpf(bot);
            if (isCtr) r = fmaxf(r, 1e-3f);
            const float base = 69.31471805599453f * __builtin_amdgcn_logf(r);

            float sv[8], cv[8];
#pragma unroll
            for (int j = 0; j < 8; ++j)
                fast_sincos(base * dimm[j], &sv[j], &cv[j]);

            F16x8 As_, Ac_;
#pragma unroll
            for (int jj = 0; jj < 4; ++jj) {
                As_.p[jj] = __builtin_amdgcn_cvt_pkrtz(sv[2 * jj], sv[2 * jj + 1]);
                Ac_.p[jj] = __builtin_amdgcn_cvt_pkrtz(cv[2 * jj], cv[2 * jj + 1]);
            }

            f32x4 acc = {};
            acc = __builtin_amdgcn_mfma_f32_16x16x32_f16(As_.v, Bs_.v, acc, 0, 0, 0);
            acc = __builtin_amdgcn_mfma_f32_16x16x32_f16(Ac_.v, Bc_.v, acc, 0, 0, 0);

            const int mrow = m0 + quad * 4;
            const int4 mk = *(const int4*)(mask + b * Nv + mrow);
            if (n < Hv) {
                const int* mkp = (const int*)&mk;
                const int pos0 = quad * 64 + (w * 4 + i);
#pragma unroll
                for (int rr = 0; rr < 4; ++rr) {
                    const float val = fmaxf(acc[rr] + bias_n, 1e-6f);
                    const float lb = fast_log(val) + (mkp[rr] ? 0.0f : -30000.0f);
                    Lst[n][pos0 + rr * 16] = f2h(lb);
                }
            }
        }

        __syncthreads();
        const int h = t >> 5, c = t & 31;
        unsigned short* dst = (unsigned short*)LB +
                              ((size_t)(b * Hv + h) * Nv + q) * Nv + c * 8;
        *(int4*)dst = *(const int4*)&Lst[h][c * 8];

    } else {
        // ================= weight transpose fp32 W[k][n] -> f16 Wt[n][k] =====
        float (*T)[65] = (float (*)[65])smraw;
        const int i = bid - 4096;          // 0..255
        const int z = i >> 6;
        const int rem = i & 63;
        const int n0 = (rem & 7) * 64, k0 = (rem >> 3) * 64;
        const float* W = (z == 0) ? Wq : (z == 1) ? Wk : (z == 2) ? Wv : Wo;
        const float* b = (z == 0) ? bq : (z == 1) ? bk : (z == 2) ? bv : bo;
        const int col = t & 63, rb = t >> 6;
#pragma unroll
        for (int j = 0; j < 16; ++j) {
            const int row = j * 4 + rb;
            T[row][col] = W[(k0 + row) * Dv + n0 + col];
        }
        __syncthreads();
#pragma unroll
        for (int j = 0; j < 16; ++j) {
            const int row = j * 4 + rb;
            Wt[z * (Dv * Dv) + (n0 + row) * Dv + k0 + col] = f2h(T[col][row]);
        }
        if (rem == 0) {
            biasStack[z * Dv + t]       = b[t];
            biasStack[z * Dv + t + 256] = b[t + 256];
        }
    }
}

// ---------------------------------------------------------------------------
// Fused Q/K/V projection GEMM, fp32-A-direct with COALESCED staging:
// thread t -> row t>>3, float4-col t&7 (8 lanes cover one contiguous 128B
// row segment -> 8 lines/instr, vs R13's 32).  Loads issued pre-barrier to
// overlap previous iteration's MFMAs.  128x64 tile, grid (8,32,3).
// z=0: Q f16 scaled 1/8; z=1: K f16; z=2: V f16 transposed [b][d][m].
// ---------------------------------------------------------------------------
__global__ __launch_bounds__(256) void qkv_gemm_kernel(
    const float* __restrict__ xq, const float* __restrict__ xk,
    const float* __restrict__ xv, const unsigned short* __restrict__ Wt,
    const float* __restrict__ bst, unsigned short* __restrict__ Qb2,
    unsigned short* __restrict__ Kb2, unsigned short* __restrict__ Vt2)
{
    const int z = blockIdx.z;
    const float* A = (z == 0) ? xq : (z == 1) ? xk : xv;
    const unsigned short* Wz = Wt + (size_t)z * (Dv * Dv);
    const float* bias = bst + z * Dv;

    const int n0 = blockIdx.x * 64;
    const int m0 = blockIdx.y * 128;
    const int t = threadIdx.x;
    const int w = t >> 6, lane = t & 63;
    const int wm = w & 1, wn = w >> 1;

    __shared__ unsigned short As[128][32];   // f16
    __shared__ unsigned short Bs[64][32];    // f16

    f32x4 acc[4][2] = {};

    const int ar = t >> 3;                   // 0..31 (+32p)
    const int ac = (t & 7) * 4;              // float4 col
    const int sr = lane >> 2;                // B staging (global_load_lds)
    const int sk = (lane & 3) * 8;
    const int fr = lane & 15;
    const int fk = (lane >> 4) * 8;

    for (int k0 = 0; k0 < Dv; k0 += 32) {
        // coalesced fp32 A loads, issued before the barrier
        float4 av[4];
#pragma unroll
        for (int p = 0; p < 4; ++p)
            av[p] = *(const float4*)(A + (size_t)(m0 + ar + 32 * p) * Dv + k0 + ac);
        __syncthreads();   // previous iteration's LDS reads complete
        gload_lds16(Wz + (size_t)(n0 + w * 16 + sr) * Dv + k0 + sk, &Bs[w * 16][0]);
#pragma unroll
        for (int p = 0; p < 4; ++p) {
            union { fp16x2 h[2]; ushort4 u; } o;
            o.h[0] = __builtin_amdgcn_cvt_pkrtz(av[p].x, av[p].y);
            o.h[1] = __builtin_amdgcn_cvt_pkrtz(av[p].z, av[p].w);
            *(ushort4*)&As[ar + 32 * p][ac] = o.u;
        }
        __syncthreads();

        fp16x8 af[4], bfr[2];
#pragma unroll
        for (int mt = 0; mt < 4; ++mt)
            af[mt] = *(const fp16x8*)&As[wm * 64 + mt * 16 + fr][fk];
#pragma unroll
        for (int nt = 0; nt < 2; ++nt)
            bfr[nt] = *(const fp16x8*)&Bs[wn * 32 + nt * 16 + fr][fk];
#pragma unroll
        for (int mt = 0; mt < 4; ++mt)
#pragma unroll
            for (int nt = 0; nt < 2; ++nt)
                acc[mt][nt] = __builtin_amdgcn_mfma_f32_16x16x32_f16(
                    af[mt], bfr[nt], acc[mt][nt], 0, 0, 0);
    }

    const int er = (lane >> 4) * 4;
    const int ec = lane & 15;
    const float scale = (z == 0) ? 0.125f : 1.0f;
#pragma unroll
    for (int nt = 0; nt < 2; ++nt) {
        const int gn = n0 + wn * 32 + nt * 16 + ec;
        const float bv_ = bias[gn];
#pragma unroll
        for (int mt = 0; mt < 4; ++mt) {
            const int gm = m0 + wm * 64 + mt * 16 + er;
            if (z == 2) {
                union { fp16x2 p[2]; ushort4 u; } o;
                o.p[0] = __builtin_amdgcn_cvt_pkrtz(acc[mt][nt][0] + bv_,
                                                    acc[mt][nt][1] + bv_);
                o.p[1] = __builtin_amdgcn_cvt_pkrtz(acc[mt][nt][2] + bv_,
                                                    acc[mt][nt][3] + bv_);
                *(ushort4*)(Vt2 + ((size_t)(gm >> 8) * Dv + gn) * Nv + (gm & 255)) = o.u;
            } else {
                unsigned short* cp = ((z == 0) ? Qb2 : Kb2) + (size_t)gm * Dv + gn;
#pragma unroll
                for (int r = 0; r < 4; ++r)
                    cp[(size_t)r * Dv] = f2h((acc[mt][nt][r] + bv_) * scale);
            }
        }
    }
}

// ---------------------------------------------------------------------------
// Output GEMM: out[4096][512] = CTXh(f16) @ Wo^T + bias, fp32.  128x64 tile,
// grid (8,32) = 256 blocks.
// ---------------------------------------------------------------------------
__global__ __launch_bounds__(256) void out_gemm_kernel(
    const unsigned short* __restrict__ A, const unsigned short* __restrict__ Wz,
    const float* __restrict__ bias, float* __restrict__ C)
{
    const int n0 = blockIdx.x * 64;
    const int m0 = blockIdx.y * 128;
    const int t = threadIdx.x;
    const int w = t >> 6, lane = t & 63;
    const int wm = w & 1, wn = w >> 1;

    __shared__ unsigned short As[128][32];
    __shared__ unsigned short Bs[64][32];

    f32x4 acc[4][2] = {};

    const int sr = lane >> 2;
    const int sk = (lane & 3) * 8;
    const int fr = lane & 15;
    const int fk = (lane >> 4) * 8;

    for (int k0 = 0; k0 < Dv; k0 += 32) {
        __syncthreads();
#pragma unroll
        for (int j = 0; j < 2; ++j) {
            const int row = w * 32 + j * 16 + sr;
            gload_lds16(A + (size_t)(m0 + row) * Dv + k0 + sk, &As[w * 32 + j * 16][0]);
        }
        gload_lds16(Wz + (size_t)(n0 + w * 16 + sr) * Dv + k0 + sk, &Bs[w * 16][0]);
        __syncthreads();

        fp16x8 af[4], bfr[2];
#pragma unroll
        for (int mt = 0; mt < 4; ++mt)
            af[mt] = *(const fp16x8*)&As[wm * 64 + mt * 16 + fr][fk];
#pragma unroll
        for (int nt = 0; nt < 2; ++nt)
            bfr[nt] = *(const fp16x8*)&Bs[wn * 32 + nt * 16 + fr][fk];
#pragma unroll
        for (int mt = 0; mt < 4; ++mt)
#pragma unroll
            for (int nt = 0; nt < 2; ++nt)
                acc[mt][nt] = __builtin_amdgcn_mfma_f32_16x16x32_f16(
                    af[mt], bfr[nt], acc[mt][nt], 0, 0, 0);
    }

    const int er = (lane >> 4) * 4;
    const int ec = lane & 15;
#pragma unroll
    for (int nt = 0; nt < 2; ++nt) {
        const int gn = n0 + wn * 32 + nt * 16 + ec;
        const float bv_ = bias[gn];
#pragma unroll
        for (int mt = 0; mt < 4; ++mt) {
            const int gm = m0 + wm * 64 + mt * 16 + er;
            float* cp = C + (size_t)gm * Dv + gn;
#pragma unroll
            for (int r = 0; r < 4; ++r)
                cp[(size_t)r * Dv] = acc[mt][nt][r] + bv_;
        }
    }
}

// ---------------------------------------------------------------------------
// attn3 (MFMA, f16): block=(64q, h, b), 4 waves; wave owns 16 q rows.
// LB (permuted) preloaded as MFMA C accumulator; Q pre-scaled 1/8.
// Softmax in registers (HW v_exp/v_rcp); P -> LDS (aliasing dead K); PV vs V^T.
// ---------------------------------------------------------------------------
__global__ __launch_bounds__(256) void attn3_kernel(
    const unsigned short* __restrict__ Qb2, const unsigned short* __restrict__ Kb2,
    const unsigned short* __restrict__ Vt2, const __half* __restrict__ LB,
    unsigned short* __restrict__ CTXh)
{
    const int qt = blockIdx.x, h = blockIdx.y, b = blockIdx.z;
    const int q0 = qt * 64;
    const int t = threadIdx.x, w = t >> 6, lane = t & 63;
    const int fr = lane & 15, fq = lane >> 4;

    __shared__ unsigned short Qs[64][72];
    __shared__ unsigned short Ks[256][72];
    __shared__ unsigned short Vt[64][264];
    unsigned short (*Pb)[264] = (unsigned short (*)[264])&Ks[0][0];

#pragma unroll
    for (int i = 0; i < 2; ++i) {          // Q
        const int idx = t + i * 256;
        const int row = idx >> 3, cu = idx & 7;
        *(int4*)&Qs[row][cu * 8] =
            *(const int4*)(Qb2 + (size_t)(b * Nv + q0 + row) * Dv + h * 64 + cu * 8);
    }
#pragma unroll
    for (int i = 0; i < 8; ++i) {          // K
        const int idx = t + i * 256;
        const int row = idx >> 3, cu = idx & 7;
        *(int4*)&Ks[row][cu * 8] =
            *(const int4*)(Kb2 + (size_t)(b * Nv + row) * Dv + h * 64 + cu * 8);
    }
#pragma unroll
    for (int i = 0; i < 8; ++i) {          // V^T
        const int idx = t + i * 256;
        const int row = idx >> 5, cu = idx & 31;
        *(int4*)&Vt[row][cu * 8] =
            *(const int4*)(Vt2 + (size_t)b * (Dv * Nv) + (h * 64 + row) * Nv + cu * 8);
    }

    // ---- acc init from permuted LB: row q=qb+r, 16 contiguous halfs @ fr*16
    f32x4 acc[16];
    const int qb = q0 + w * 16 + fq * 4;
    const __half* lbp = LB + ((size_t)(b * Hv + h) * Nv + qb) * Nv + fr * 16;
#pragma unroll
    for (int r = 0; r < 4; ++r) {
        union { int4 v; __half hs[8]; } u0, u1;
        const int4* p = (const int4*)(lbp + (size_t)r * Nv);
        u0.v = p[0]; u1.v = p[1];
#pragma unroll
        for (int nt = 0; nt < 8; ++nt) acc[nt][r]     = __half2float(u0.hs[nt]);
#pragma unroll
        for (int nt = 0; nt < 8; ++nt) acc[nt + 8][r] = __half2float(u1.hs[nt]);
    }

    __syncthreads();

    // ---- QK^T ----
    const fp16x8 aq0 = *(const fp16x8*)&Qs[w * 16 + fr][fq * 8];
    const fp16x8 aq1 = *(const fp16x8*)&Qs[w * 16 + fr][32 + fq * 8];
#pragma unroll
    for (int nt = 0; nt < 16; ++nt) {
        const fp16x8 bk0 = *(const fp16x8*)&Ks[nt * 16 + fr][fq * 8];
        const fp16x8 bk1 = *(const fp16x8*)&Ks[nt * 16 + fr][32 + fq * 8];
        acc[nt] = __builtin_amdgcn_mfma_f32_16x16x32_f16(aq0, bk0, acc[nt], 0, 0, 0);
        acc[nt] = __builtin_amdgcn_mfma_f32_16x16x32_f16(aq1, bk1, acc[nt], 0, 0, 0);
    }

    // ---- softmax in registers (HW exp2/rcp) ----
    float ri[4];
#pragma unroll
    for (int r = 0; r < 4; ++r) {
        float mx = acc[0][r];
#pragma unroll
        for (int nt = 1; nt < 16; ++nt) mx = fmaxf(mx, acc[nt][r]);
        mx = fmaxf(mx, __shfl_xor(mx, 1));
        mx = fmaxf(mx, __shfl_xor(mx, 2));
        mx = fmaxf(mx, __shfl_xor(mx, 4));
        mx = fmaxf(mx, __shfl_xor(mx, 8));
        float s = 0.0f;
#pragma unroll
        for (int nt = 0; nt < 16; ++nt) {
            const float e = fast_exp(acc[nt][r] - mx);
            acc[nt][r] = e;
            s += e;
        }
        s += __shfl_xor(s, 1);
        s += __shfl_xor(s, 2);
        s += __shfl_xor(s, 4);
        s += __shfl_xor(s, 8);
        ri[r] = __builtin_amdgcn_rcpf(s);
    }

    __syncthreads();   // all Ks reads complete before P overwrites the buffer

#pragma unroll
    for (int nt = 0; nt < 16; ++nt)
#pragma unroll
        for (int r = 0; r < 4; ++r)
            Pb[w * 16 + fq * 4 + r][nt * 16 + fr] = f2h(acc[nt][r] * ri[r]);

    // ---- PV ----
    f32x4 o[4] = {};
#pragma unroll
    for (int kt = 0; kt < 8; ++kt) {
        const fp16x8 ap = *(const fp16x8*)&Pb[w * 16 + fr][kt * 32 + fq * 8];
#pragma unroll
        for (int nt2 = 0; nt2 < 4; ++nt2) {
            const fp16x8 bv_ = *(const fp16x8*)&Vt[nt2 * 16 + fr][kt * 32 + fq * 8];
            o[nt2] = __builtin_amdgcn_mfma_f32_16x16x32_f16(ap, bv_, o[nt2], 0, 0, 0);
        }
    }

#pragma unroll
    for (int nt2 = 0; nt2 < 4; ++nt2)
#pragma unroll
        for (int r = 0; r < 4; ++r)
            CTXh[(size_t)(b * Nv + qb + r) * Dv + h * 64 + nt2 * 16 + fr] =
                f2h(o[nt2][r]);
}

// ---------------------------------------------------------------------------
extern "C" void kernel_launch(void* const* d_in, const int* in_sizes, int n_in,
                              void* d_out, int out_size, void* d_ws, size_t ws_size,
                              hipStream_t stream) {
    (void)in_sizes; (void)n_in; (void)out_size; (void)ws_size;

    const float* inq  = (const float*)d_in[0];
    const float* ink  = (const float*)d_in[1];
    const float* inv  = (const float*)d_in[2];
    const float* box  = (const float*)d_in[3];
    const int*   mask = (const int*)d_in[4];
    const float* Wq   = (const float*)d_in[5];
    const float* bq   = (const float*)d_in[6];
    const float* Wk   = (const float*)d_in[7];
    const float* bk   = (const float*)d_in[8];
    const float* Wv   = (const float*)d_in[9];
    const float* bv   = (const float*)d_in[10];
    const float* Wo   = (const float*)d_in[11];
    const float* bo   = (const float*)d_in[12];
    const float* WGw  = (const float*)d_in[13];
    const float* WGb  = (const float*)d_in[14];

    char* W = (char*)d_ws;
    const size_t MB = 1048576;
    unsigned short* Qb2  = (unsigned short*)(W + 0);        // 4 MB f16, pre-scaled 1/8
    unsigned short* Kb2  = (unsigned short*)(W + 4 * MB);   // 4 MB f16
    unsigned short* Vt2  = (unsigned short*)(W + 8 * MB);   // 4 MB f16 [b][d][m]
    unsigned short* Wt   = (unsigned short*)(W + 12 * MB);  // 2 MB (4 transposed f16 weights)
    float*          bst  = (float*)(W + 14 * MB);           // 8 KB
    unsigned short* CTXh = (unsigned short*)(W + 15 * MB);  // 4 MB f16
    __half*         LB   = (__half*)(W + 20 * MB);          // 16.8 MB

    float* out = (float*)d_out;

    mega1_kernel<<<4352, 256, 0, stream>>>(
        box, mask, WGw, WGb, LB,
        Wq, Wk, Wv, Wo, bq, bk, bv, bo, Wt, bst);

    qkv_gemm_kernel<<<dim3(8, 32, 3), 256, 0, stream>>>(
        inq, ink, inv, Wt, bst, Qb2, Kb2, Vt2);

    attn3_kernel<<<dim3(4, 8, 16), 256, 0, stream>>>(Qb2, Kb2, Vt2, LB, CTXh);

    out_gemm_kernel<<<dim3(8, 32), 256, 0, stream>>>(CTXh, Wt + 3 * (Dv * Dv), bst + 3 * Dv, out);
}

// Round 15
// 156.616 us; speedup vs baseline: 1.0655x; 1.0652x over previous
//
#include <hip/hip_runtime.h>
#include <hip/hip_fp16.h>
#include <math.h>

#define Bv   16
#define Nv   256
#define Dv   512
#define Hv   8
#define MNv  4096          // B*N tokens

typedef __attribute__((ext_vector_type(8))) short bf16x8;
typedef __attribute__((ext_vector_type(4))) float f32x4;
typedef __fp16 fp16x8 __attribute__((ext_vector_type(8)));
typedef __fp16 fp16x2 __attribute__((ext_vector_type(2)));

__device__ __forceinline__ unsigned short f2bf(float f) {   // RNE
    unsigned u = __float_as_uint(f);
    u = u + 0x7FFFu + ((u >> 16) & 1u);
    return (unsigned short)(u >> 16);
}
__device__ __forceinline__ void gload_lds16(const void* g, void* l) {
    __builtin_amdgcn_global_load_lds(
        (const __attribute__((address_space(1))) unsigned int*)g,
        (__attribute__((address_space(3))) unsigned int*)l, 16, 0, 0);
}

// Raw HW transcendentals.
__device__ __forceinline__ void fast_sincos(float x, float* s, float* c) {
    const float rev = x * 0.15915494309189535f;   // v_sin takes revolutions
    const float fr  = rev - floorf(rev);
    *s = __builtin_amdgcn_sinf(fr);
    *c = __builtin_amdgcn_cosf(fr);
}
__device__ __forceinline__ float fast_log(float x) {
    return __builtin_amdgcn_logf(x) * 0.6931471805599453f;
}
__device__ __forceinline__ float fast_exp(float x) {
    return __builtin_amdgcn_exp2f(x * 1.4426950408889634f);
}

// ---------------------------------------------------------------------------
// MEGA-1: geo-bias (blocks 0..4095) + fp32->bf16 input conv (4096..10239)
// + weight transpose conv (10240..10495), one launch.
// ---------------------------------------------------------------------------
__global__ __launch_bounds__(256) void mega1_kernel(
    const float* __restrict__ box, const int* __restrict__ mask,
    const float* __restrict__ WGw, const float* __restrict__ WGb,
    __half* __restrict__ LB,
    const float* __restrict__ xq, const float* __restrict__ xk,
    const float* __restrict__ xv, unsigned short* __restrict__ Ab,
    const float* __restrict__ Wq, const float* __restrict__ Wk,
    const float* __restrict__ Wv, const float* __restrict__ Wo,
    const float* __restrict__ bq, const float* __restrict__ bk,
    const float* __restrict__ bv, const float* __restrict__ bo,
    unsigned short* __restrict__ Wt, float* __restrict__ biasStack)
{
    __shared__ __align__(16) char smraw[64 * 65 * 4];   // union: geo Lst / conv_w T
    const int bid = blockIdx.x;
    const int t = threadIdx.x;

    if (bid < 4096) {
        // ================= geo-bias =================
        unsigned short (*Lst)[264] = (unsigned short (*)[264])smraw;
        const int q = bid & 255;
        const int b = bid >> 8;
        const int w = t >> 6, lane = t & 63;
        const int n = lane & 15;
        const int quad = lane >> 4;

        const float4 bq_ = *(const float4*)(box + (b * Nv + q) * 4);
        const float cxq = (bq_.x + bq_.z) * 0.5f;
        const float cyq = (bq_.y + bq_.w) * 0.5f;
        const float wq  = bq_.z - bq_.x + 1.0f;
        const float hq  = bq_.w - bq_.y + 1.0f;

        union F16x8 { fp16x8 v; fp16x2 p[4]; };
        F16x8 Bs_, Bc_;
        Bs_.v = (fp16x8){}; Bc_.v = (fp16x8){};
        float bias_n = 0.0f;
        if (n < Hv) {
            bias_n = WGb[n];
#pragma unroll
            for (int jj = 0; jj < 4; ++jj) {
                Bs_.p[jj] = __builtin_amdgcn_cvt_pkrtz(WGw[n * 64 + quad * 8 + 2 * jj],
                                                       WGw[n * 64 + quad * 8 + 2 * jj + 1]);
                Bc_.p[jj] = __builtin_amdgcn_cvt_pkrtz(WGw[n * 64 + 32 + quad * 8 + 2 * jj],
                                                       WGw[n * 64 + 32 + quad * 8 + 2 * jj + 1]);
            }
        }

        const float dimm[8] = {1.0f, 0.42169650342f, 0.17782794100f, 0.07498942093f,
                               0.03162277660f, 0.01333521432f, 0.00562341325f, 0.00237137371f};
        const bool isCtr = (quad < 2);
        const bool isY   = (quad & 1);
        const float cq  = isY ? cyq : cxq;
        const float sq_ = isY ? hq : wq;

#pragma unroll
        for (int i = 0; i < 4; ++i) {
            const int m0 = (w * 4 + i) * 16;
            const float4 bm = *(const float4*)(box + (b * Nv + m0 + n) * 4);
            const float cxm = (bm.x + bm.z) * 0.5f;
            const float cym = (bm.y + bm.w) * 0.5f;
            const float wm  = bm.z - bm.x + 1.0f;
            const float hm  = bm.w - bm.y + 1.0f;
            const float cm_ = isY ? cym : cxm;
            const float sm_ = isY ? hm : wm;
            const float top = isCtr ? fabsf(cq - cm_) : sq_;
            const float bot = isCtr ? sq_ : sm_;
            float r = top * __builtin_amdgcn_rcpf(bot);
            if (isCtr) r = fmaxf(r, 1e-3f);
            const float base = 69.31471805599453f * __builtin_amdgcn_logf(r);

            float sv[8], cv[8];
#pragma unroll
            for (int j = 0; j < 8; ++j)
                fast_sincos(base * dimm[j], &sv[j], &cv[j]);

            F16x8 As_, Ac_;
#pragma unroll
            for (int jj = 0; jj < 4; ++jj) {
                As_.p[jj] = __builtin_amdgcn_cvt_pkrtz(sv[2 * jj], sv[2 * jj + 1]);
                Ac_.p[jj] = __builtin_amdgcn_cvt_pkrtz(cv[2 * jj], cv[2 * jj + 1]);
            }

            f32x4 acc = {};
            acc = __builtin_amdgcn_mfma_f32_16x16x32_f16(As_.v, Bs_.v, acc, 0, 0, 0);
            acc = __builtin_amdgcn_mfma_f32_16x16x32_f16(Ac_.v, Bc_.v, acc, 0, 0, 0);

            const int mrow = m0 + quad * 4;
            const int4 mk = *(const int4*)(mask + b * Nv + mrow);
            if (n < Hv) {
                const int* mkp = (const int*)&mk;
                const int pos0 = quad * 64 + (w * 4 + i);
#pragma unroll
                for (int rr = 0; rr < 4; ++rr) {
                    const float val = fmaxf(acc[rr] + bias_n, 1e-6f);
                    const float lb = fast_log(val) + (mkp[rr] ? 0.0f : -30000.0f);
                    Lst[n][pos0 + rr * 16] = __half_as_ushort(__float2half(lb));
                }
            }
        }

        __syncthreads();
        const int h = t >> 5, c = t & 31;
        unsigned short* dst = (unsigned short*)LB +
                              ((size_t)(b * Hv + h) * Nv + q) * Nv + c * 8;
        *(int4*)dst = *(const int4*)&Lst[h][c * 8];

    } else if (bid < 10240) {
        // ================= input fp32 -> bf16 =================
        const int i = bid - 4096;
        const int z = i >> 11;            // 0..2
        const int xblk = i & 2047;
        const float* src = (z == 0) ? xq : (z == 1) ? xk : xv;
        const size_t base = (size_t)z * (MNv * Dv);
        const int idx = (xblk * 256 + t) * 4;
        float4 x = *(const float4*)(src + idx);
        ushort4 h4;
        h4.x = f2bf(x.x); h4.y = f2bf(x.y); h4.z = f2bf(x.z); h4.w = f2bf(x.w);
        *(ushort4*)(Ab + base + idx) = h4;

    } else {
        // ================= weight transpose (fp32 W[k][n] -> bf16 Wt[n][k]) =====
        float (*T)[65] = (float (*)[65])smraw;
        const int i = bid - 10240;        // 0..255
        const int z = i >> 6;
        const int rem = i & 63;
        const int n0 = (rem & 7) * 64, k0 = (rem >> 3) * 64;
        const float* W = (z == 0) ? Wq : (z == 1) ? Wk : (z == 2) ? Wv : Wo;
        const float* b = (z == 0) ? bq : (z == 1) ? bk : (z == 2) ? bv : bo;
        const int col = t & 63, rb = t >> 6;
#pragma unroll
        for (int j = 0; j < 16; ++j) {
            const int row = j * 4 + rb;
            T[row][col] = W[(k0 + row) * Dv + n0 + col];
        }
        __syncthreads();
#pragma unroll
        for (int j = 0; j < 16; ++j) {
            const int row = j * 4 + rb;
            Wt[z * (Dv * Dv) + (n0 + row) * Dv + k0 + col] = f2bf(T[col][row]);
        }
        if (rem == 0) {
            biasStack[z * Dv + t]       = b[t];
            biasStack[z * Dv + t + 256] = b[t + 256];
        }
    }
}

// ---------------------------------------------------------------------------
// Fused Q/K/V projection GEMM, 128x64 tile, grid (8,32,3) = 768 blocks.
// z=0: Q bf16 scaled 1/8; z=1: K bf16; z=2: V bf16 transposed [b][d][m].
// ---------------------------------------------------------------------------
__global__ __launch_bounds__(256) void qkv_gemm_kernel(
    const unsigned short* __restrict__ Ab, const unsigned short* __restrict__ Wt,
    const float* __restrict__ bst, unsigned short* __restrict__ Qb2,
    unsigned short* __restrict__ Kb2, unsigned short* __restrict__ Vt2)
{
    const int z = blockIdx.z;
    const unsigned short* A = Ab + (size_t)z * (MNv * Dv);
    const unsigned short* Wz = Wt + (size_t)z * (Dv * Dv);
    const float* bias = bst + z * Dv;

    const int n0 = blockIdx.x * 64;
    const int m0 = blockIdx.y * 128;
    const int t = threadIdx.x;
    const int w = t >> 6, lane = t & 63;
    const int wm = w & 1, wn = w >> 1;

    __shared__ unsigned short As[128][32];
    __shared__ unsigned short Bs[64][32];

    f32x4 acc[4][2] = {};

    const int sr = lane >> 2;
    const int sk = (lane & 3) * 8;
    const int fr = lane & 15;
    const int fk = (lane >> 4) * 8;

    for (int k0 = 0; k0 < Dv; k0 += 32) {
        __syncthreads();
#pragma unroll
        for (int j = 0; j < 2; ++j) {
            const int row = w * 32 + j * 16 + sr;
            gload_lds16(A + (size_t)(m0 + row) * Dv + k0 + sk, &As[w * 32 + j * 16][0]);
        }
        gload_lds16(Wz + (size_t)(n0 + w * 16 + sr) * Dv + k0 + sk, &Bs[w * 16][0]);
        __syncthreads();

        bf16x8 af[4], bfr[2];
#pragma unroll
        for (int mt = 0; mt < 4; ++mt)
            af[mt] = *(const bf16x8*)&As[wm * 64 + mt * 16 + fr][fk];
#pragma unroll
        for (int nt = 0; nt < 2; ++nt)
            bfr[nt] = *(const bf16x8*)&Bs[wn * 32 + nt * 16 + fr][fk];
#pragma unroll
        for (int mt = 0; mt < 4; ++mt)
#pragma unroll
            for (int nt = 0; nt < 2; ++nt)
                acc[mt][nt] = __builtin_amdgcn_mfma_f32_16x16x32_bf16(
                    af[mt], bfr[nt], acc[mt][nt], 0, 0, 0);
    }

    const int er = (lane >> 4) * 4;
    const int ec = lane & 15;
    const float scale = (z == 0) ? 0.125f : 1.0f;
#pragma unroll
    for (int nt = 0; nt < 2; ++nt) {
        const int gn = n0 + wn * 32 + nt * 16 + ec;
        const float bv_ = bias[gn];
#pragma unroll
        for (int mt = 0; mt < 4; ++mt) {
            const int gm = m0 + wm * 64 + mt * 16 + er;
            if (z == 2) {
                ushort4 o;
                o.x = f2bf(acc[mt][nt][0] + bv_);
                o.y = f2bf(acc[mt][nt][1] + bv_);
                o.z = f2bf(acc[mt][nt][2] + bv_);
                o.w = f2bf(acc[mt][nt][3] + bv_);
                *(ushort4*)(Vt2 + ((size_t)(gm >> 8) * Dv + gn) * Nv + (gm & 255)) = o;
            } else {
                unsigned short* cp = ((z == 0) ? Qb2 : Kb2) + (size_t)gm * Dv + gn;
#pragma unroll
                for (int r = 0; r < 4; ++r)
                    cp[(size_t)r * Dv] = f2bf((acc[mt][nt][r] + bv_) * scale);
            }
        }
    }
}

// ---------------------------------------------------------------------------
// Output GEMM: out[4096][512] = CTXb @ Wo^T + bias, fp32.  128x64 tile,
// grid (8,32) = 256 blocks.
// ---------------------------------------------------------------------------
__global__ __launch_bounds__(256) void out_gemm_kernel(
    const unsigned short* __restrict__ A, const unsigned short* __restrict__ Wz,
    const float* __restrict__ bias, float* __restrict__ C)
{
    const int n0 = blockIdx.x * 64;
    const int m0 = blockIdx.y * 128;
    const int t = threadIdx.x;
    const int w = t >> 6, lane = t & 63;
    const int wm = w & 1, wn = w >> 1;

    __shared__ unsigned short As[128][32];
    __shared__ unsigned short Bs[64][32];

    f32x4 acc[4][2] = {};

    const int sr = lane >> 2;
    const int sk = (lane & 3) * 8;
    const int fr = lane & 15;
    const int fk = (lane >> 4) * 8;

    for (int k0 = 0; k0 < Dv; k0 += 32) {
        __syncthreads();
#pragma unroll
        for (int j = 0; j < 2; ++j) {
            const int row = w * 32 + j * 16 + sr;
            gload_lds16(A + (size_t)(m0 + row) * Dv + k0 + sk, &As[w * 32 + j * 16][0]);
        }
        gload_lds16(Wz + (size_t)(n0 + w * 16 + sr) * Dv + k0 + sk, &Bs[w * 16][0]);
        __syncthreads();

        bf16x8 af[4], bfr[2];
#pragma unroll
        for (int mt = 0; mt < 4; ++mt)
            af[mt] = *(const bf16x8*)&As[wm * 64 + mt * 16 + fr][fk];
#pragma unroll
        for (int nt = 0; nt < 2; ++nt)
            bfr[nt] = *(const bf16x8*)&Bs[wn * 32 + nt * 16 + fr][fk];
#pragma unroll
        for (int mt = 0; mt < 4; ++mt)
#pragma unroll
            for (int nt = 0; nt < 2; ++nt)
                acc[mt][nt] = __builtin_amdgcn_mfma_f32_16x16x32_bf16(
                    af[mt], bfr[nt], acc[mt][nt], 0, 0, 0);
    }

    const int er = (lane >> 4) * 4;
    const int ec = lane & 15;
#pragma unroll
    for (int nt = 0; nt < 2; ++nt) {
        const int gn = n0 + wn * 32 + nt * 16 + ec;
        const float bv_ = bias[gn];
#pragma unroll
        for (int mt = 0; mt < 4; ++mt) {
            const int gm = m0 + wm * 64 + mt * 16 + er;
            float* cp = C + (size_t)gm * Dv + gn;
#pragma unroll
            for (int r = 0; r < 4; ++r)
                cp[(size_t)r * Dv] = acc[mt][nt][r] + bv_;
        }
    }
}

// ---------------------------------------------------------------------------
// attn3 (MFMA): block=(64q, h, b), 4 waves; wave owns 16 q rows.
// LB (permuted) preloaded as MFMA C accumulator; Q pre-scaled 1/8.
// Softmax in registers (HW v_exp/v_rcp); P -> LDS (aliasing dead K); PV vs V^T.
// ---------------------------------------------------------------------------
__global__ __launch_bounds__(256) void attn3_kernel(
    const unsigned short* __restrict__ Qb2, const unsigned short* __restrict__ Kb2,
    const unsigned short* __restrict__ Vt2, const __half* __restrict__ LB,
    unsigned short* __restrict__ CTXb)
{
    const int qt = blockIdx.x, h = blockIdx.y, b = blockIdx.z;
    const int q0 = qt * 64;
    const int t = threadIdx.x, w = t >> 6, lane = t & 63;
    const int fr = lane & 15, fq = lane >> 4;

    __shared__ unsigned short Qs[64][72];
    __shared__ unsigned short Ks[256][72];
    __shared__ unsigned short Vt[64][264];
    unsigned short (*Pb)[264] = (unsigned short (*)[264])&Ks[0][0];

#pragma unroll
    for (int i = 0; i < 2; ++i) {          // Q
        const int idx = t + i * 256;
        const int row = idx >> 3, cu = idx & 7;
        *(bf16x8*)&Qs[row][cu * 8] =
            *(const bf16x8*)(Qb2 + (size_t)(b * Nv + q0 + row) * Dv + h * 64 + cu * 8);
    }
#pragma unroll
    for (int i = 0; i < 8; ++i) {          // K
        const int idx = t + i * 256;
        const int row = idx >> 3, cu = idx & 7;
        *(bf16x8*)&Ks[row][cu * 8] =
            *(const bf16x8*)(Kb2 + (size_t)(b * Nv + row) * Dv + h * 64 + cu * 8);
    }
#pragma unroll
    for (int i = 0; i < 8; ++i) {          // V^T
        const int idx = t + i * 256;
        const int row = idx >> 5, cu = idx & 31;
        *(bf16x8*)&Vt[row][cu * 8] =
            *(const bf16x8*)(Vt2 + (size_t)b * (Dv * Nv) + (h * 64 + row) * Nv + cu * 8);
    }

    // ---- acc init from permuted LB: row q=qb+r, 16 contiguous halfs @ fr*16
    f32x4 acc[16];
    const int qb = q0 + w * 16 + fq * 4;
    const __half* lbp = LB + ((size_t)(b * Hv + h) * Nv + qb) * Nv + fr * 16;
#pragma unroll
    for (int r = 0; r < 4; ++r) {
        union { int4 v; __half hs[8]; } u0, u1;
        const int4* p = (const int4*)(lbp + (size_t)r * Nv);
        u0.v = p[0]; u1.v = p[1];
#pragma unroll
        for (int nt = 0; nt < 8; ++nt) acc[nt][r]     = __half2float(u0.hs[nt]);
#pragma unroll
        for (int nt = 0; nt < 8; ++nt) acc[nt + 8][r] = __half2float(u1.hs[nt]);
    }

    __syncthreads();

    // ---- QK^T ----
    const bf16x8 aq0 = *(const bf16x8*)&Qs[w * 16 + fr][fq * 8];
    const bf16x8 aq1 = *(const bf16x8*)&Qs[w * 16 + fr][32 + fq * 8];
#pragma unroll
    for (int nt = 0; nt < 16; ++nt) {
        const bf16x8 bk0 = *(const bf16x8*)&Ks[nt * 16 + fr][fq * 8];
        const bf16x8 bk1 = *(const bf16x8*)&Ks[nt * 16 + fr][32 + fq * 8];
        acc[nt] = __builtin_amdgcn_mfma_f32_16x16x32_bf16(aq0, bk0, acc[nt], 0, 0, 0);
        acc[nt] = __builtin_amdgcn_mfma_f32_16x16x32_bf16(aq1, bk1, acc[nt], 0, 0, 0);
    }

    // ---- softmax in registers (HW exp2/rcp) ----
    float ri[4];
#pragma unroll
    for (int r = 0; r < 4; ++r) {
        float mx = acc[0][r];
#pragma unroll
        for (int nt = 1; nt < 16; ++nt) mx = fmaxf(mx, acc[nt][r]);
        mx = fmaxf(mx, __shfl_xor(mx, 1));
        mx = fmaxf(mx, __shfl_xor(mx, 2));
        mx = fmaxf(mx, __shfl_xor(mx, 4));
        mx = fmaxf(mx, __shfl_xor(mx, 8));
        float s = 0.0f;
#pragma unroll
        for (int nt = 0; nt < 16; ++nt) {
            const float e = fast_exp(acc[nt][r] - mx);
            acc[nt][r] = e;
            s += e;
        }
        s += __shfl_xor(s, 1);
        s += __shfl_xor(s, 2);
        s += __shfl_xor(s, 4);
        s += __shfl_xor(s, 8);
        ri[r] = __builtin_amdgcn_rcpf(s);
    }

    __syncthreads();   // all Ks reads complete before P overwrites the buffer

#pragma unroll
    for (int nt = 0; nt < 16; ++nt)
#pragma unroll
        for (int r = 0; r < 4; ++r)
            Pb[w * 16 + fq * 4 + r][nt * 16 + fr] = f2bf(acc[nt][r] * ri[r]);

    // ---- PV ----
    f32x4 o[4] = {};
#pragma unroll
    for (int kt = 0; kt < 8; ++kt) {
        const bf16x8 ap = *(const bf16x8*)&Pb[w * 16 + fr][kt * 32 + fq * 8];
#pragma unroll
        for (int nt2 = 0; nt2 < 4; ++nt2) {
            const bf16x8 bv_ = *(const bf16x8*)&Vt[nt2 * 16 + fr][kt * 32 + fq * 8];
            o[nt2] = __builtin_amdgcn_mfma_f32_16x16x32_bf16(ap, bv_, o[nt2], 0, 0, 0);
        }
    }

#pragma unroll
    for (int nt2 = 0; nt2 < 4; ++nt2)
#pragma unroll
        for (int r = 0; r < 4; ++r)
            CTXb[(size_t)(b * Nv + qb + r) * Dv + h * 64 + nt2 * 16 + fr] =
                f2bf(o[nt2][r]);
}

// ---------------------------------------------------------------------------
extern "C" void kernel_launch(void* const* d_in, const int* in_sizes, int n_in,
                              void* d_out, int out_size, void* d_ws, size_t ws_size,
                              hipStream_t stream) {
    (void)in_sizes; (void)n_in; (void)out_size; (void)ws_size;

    const float* inq  = (const float*)d_in[0];
    const float* ink  = (const float*)d_in[1];
    const float* inv  = (const float*)d_in[2];
    const float* box  = (const float*)d_in[3];
    const int*   mask = (const int*)d_in[4];
    const float* Wq   = (const float*)d_in[5];
    const float* bq   = (const float*)d_in[6];
    const float* Wk   = (const float*)d_in[7];
    const float* bk   = (const float*)d_in[8];
    const float* Wv   = (const float*)d_in[9];
    const float* bv   = (const float*)d_in[10];
    const float* Wo   = (const float*)d_in[11];
    const float* bo   = (const float*)d_in[12];
    const float* WGw  = (const float*)d_in[13];
    const float* WGb  = (const float*)d_in[14];

    char* W = (char*)d_ws;
    const size_t MB = 1048576;
    unsigned short* Qb2  = (unsigned short*)(W + 0);        // 4 MB bf16, pre-scaled 1/8
    unsigned short* Kb2  = (unsigned short*)(W + 4 * MB);   // 4 MB bf16
    unsigned short* Vt2  = (unsigned short*)(W + 8 * MB);   // 4 MB bf16 [b][d][m]
    unsigned short* Wt   = (unsigned short*)(W + 12 * MB);  // 2 MB
    float*          bst  = (float*)(W + 14 * MB);           // 8 KB
    unsigned short* CTXb = (unsigned short*)(W + 15 * MB);  // 4 MB
    unsigned short* Ab   = (unsigned short*)(W + 20 * MB);  // 12 MB
    __half*         LB   = (__half*)(W + 32 * MB);          // 16.8 MB

    float* out = (float*)d_out;

    mega1_kernel<<<10496, 256, 0, stream>>>(
        box, mask, WGw, WGb, LB,
        inq, ink, inv, Ab,
        Wq, Wk, Wv, Wo, bq, bk, bv, bo, Wt, bst);

    qkv_gemm_kernel<<<dim3(8, 32, 3), 256, 0, stream>>>(Ab, Wt, bst, Qb2, Kb2, Vt2);

    attn3_kernel<<<dim3(4, 8, 16), 256, 0, stream>>>(Qb2, Kb2, Vt2, LB, CTXb);

    out_gemm_kernel<<<dim3(8, 32), 256, 0, stream>>>(CTXb, Wt + 3 * (Dv * Dv), bst + 3 * Dv, out);
}